// Round 14
// baseline (291.914 us; speedup 1.0000x reference)
//
#include <hip/hip_runtime.h>
#include <hip/hip_bf16.h>

typedef __attribute__((ext_vector_type(4))) float f32x4;
typedef __attribute__((ext_vector_type(8))) short bf16x8;
typedef __attribute__((ext_vector_type(4))) short bf16x4v;

#define M_DIM 8192
#define N_DIM 4096
#define K_DIM 4096
#define NX (M_DIM * K_DIM)
#define NW (N_DIM * K_DIM)

#define BM 256
#define BN 128
#define BK 32
#define NKT (K_DIM / BK)   /* 128 */
#define THREADS 256
#define SLOT_SZ 24576      /* 24 KiB ring slot: A 16 KiB + B 8 KiB */

#define GLOAD_LDS16(g, l)                                                        \
  __builtin_amdgcn_global_load_lds(                                              \
      (const __attribute__((address_space(1))) void*)(g),                        \
      (__attribute__((address_space(3))) void*)(l), 16, 0, 0)

// ---------------------------------------------------------------------------
// Pass 1: fp32 -> bf16 conversion of x and W into workspace.
// ---------------------------------------------------------------------------
__global__ __launch_bounds__(256) void convert_bf16(const float* __restrict__ x,
                                                    const float* __restrict__ w,
                                                    short* __restrict__ ws) {
  const long stride = (long)gridDim.x * blockDim.x;
  const long total8 = ((long)NX + NW) / 8;
  for (long i = blockIdx.x * (long)blockDim.x + threadIdx.x; i < total8; i += stride) {
    const long base = i * 8;
    const float* src = (base < NX) ? (x + base) : (w + (base - NX));
    short* dst = ws + base;
    f32x4 a = *(const f32x4*)src;
    f32x4 b = *(const f32x4*)(src + 4);
    bf16x8 o;
    o[0] = (short)__bfloat16_as_ushort(__float2bfloat16(a[0]));
    o[1] = (short)__bfloat16_as_ushort(__float2bfloat16(a[1]));
    o[2] = (short)__bfloat16_as_ushort(__float2bfloat16(a[2]));
    o[3] = (short)__bfloat16_as_ushort(__float2bfloat16(a[3]));
    o[4] = (short)__bfloat16_as_ushort(__float2bfloat16(b[0]));
    o[5] = (short)__bfloat16_as_ushort(__float2bfloat16(b[1]));
    o[6] = (short)__bfloat16_as_ushort(__float2bfloat16(b[2]));
    o[7] = (short)__bfloat16_as_ushort(__float2bfloat16(b[3]));
    *(bf16x8*)dst = o;
  }
}

// ---------------------------------------------------------------------------
// Pass 2: 256x128 bf16 GEMM blocks, BK=32, 4 waves (2M x 2N), ring-of-3 LDS
// (72 KiB -> 2 blocks/CU co-resident: per SIMD the 2 waves belong to
// DIFFERENT blocks, so each block's barrier stalls are covered by the other
// block's compute).  1 barrier per 32-MFMA K-tile, counted vmcnt(6)
// (2 tiles of staging flight).  Row-pair XOR swizzle for 64-B rows;
// XCD chunking; setprio; coalesced LDS-transpose epilogue.
// Y = relu(X @ W^T + b)
//
// LDS slot (24 KiB): A rows 0-255 at [0,16K), B rows 0-127 at [16K,24K).
// Row r (64 B) stored in pair-blocks: phys byte = (r>>1)*128 +
// (((r&1)*4 + s) ^ ((r>>1)&7))*16, s = 16-B slot 0..3.
// Frag reads (16 lanes, rows 0..15 of a frag): positions spread over 8
// slots -> 2 lanes/bank-range = conflict-free (2-way is free, m136).
// Staging (linear dest, 256 thr x 16 B = 4 KB = 64 rows/gload): lane t
// writes phys (t>>3)*128 + (t&7)*16; inverse swizzle gives its global
// source: h = (t&7) ^ ((t>>3)&7); row = 2*(t>>3) + (h>>2); col = (h&3)*8.
//
// Ring schedule, tile t uses slot t%3:
//   reads(t) from slot t%3; stage(t+2) into slot (t+2)%3 == (t-1)%3
//   (sealed: tile t-1's reads of that slot finished before the end-of-(t-1)
//   barrier, which precedes tile t); 32 MFMA; vmcnt(6) (waits stage(t+1)'s
//   6 loads, leaves stage(t+2)'s 6 in flight); barrier (publishes t+1).
// Tail: t=126 gates vmcnt(0) (drains stage(127)); t=127 no gate; final
// barrier before the epilogue (scratch overlaps ring slots).
// ---------------------------------------------------------------------------
__global__ __launch_bounds__(THREADS, 2) void gemm2_bf16(
    const short* __restrict__ Abf,   /* [M][K] bf16 */
    const short* __restrict__ Bbf,   /* [N][K] bf16 */
    const float* __restrict__ bias,
    float* __restrict__ Y) {
  __shared__ short lds[3 * SLOT_SZ / 2];   /* 72 KiB */
  char* const ldsb = (char*)lds;

  const int tid  = threadIdx.x;
  const int lane = tid & 63;
  const int wave = tid >> 6;       // 0..3
  const int wm   = wave >> 1;      // 0..1  (M half: 128 rows)
  const int wn   = wave & 1;       // 0..1  (N half: 64 cols)

  // XCD chunking: grid 32x32 = 1024 wgs = 8 XCDs x 128 (bijective).
  // Per-XCD super-tile: 8 by x 16 bx -> A 16 MB + B 16 MB footprint.
  const int lin = blockIdx.x + blockIdx.y * (N_DIM / BN);   // gridDim.x = 32
  const int xcd = lin & 7;
  const int idx = lin >> 3;        // 0..127
  const int by = (xcd & 3) * 8 + (idx >> 4);    // 0..31
  const int bx = (xcd >> 2) * 16 + (idx & 15);  // 0..31
  const long rowA0 = (long)by * BM;
  const long rowB0 = (long)bx * BN;

  // staging source (inverse row-pair swizzle), per-lane:
  const int h_st  = (tid & 7) ^ ((tid >> 3) & 7);
  const int voff  = (2 * (tid >> 3) + (h_st >> 2)) * K_DIM + (h_st & 3) * 8;

  const short* uA = Abf + rowA0 * (long)K_DIM;
  const short* uB = Bbf + rowB0 * (long)K_DIM;

  // fragment-read per-lane byte offset within a frag's 1-KB block:
  // row-in-frag = lane&15, s = lane>>4; phys = ((row&1)*4+s) ^ ((row>>1)&7)
  const int physoff = ((lane & 15) >> 1) * 128 +
                      ((((((lane & 1) << 2) | (lane >> 4))) ^ ((lane >> 1) & 7)) << 4);

// stage tile TT into ring slot SLOT_ (6 gloads: A 4 x 64 rows, B 2 x 64).
#define STAGE2(SLOT_, TT) do {                                                   \
    const short* ga_ = uA + (long)(TT) * BK + voff;                              \
    char* la_ = ldsb + (SLOT_) * SLOT_SZ + wave * 1024;                          \
    GLOAD_LDS16(ga_, la_);                                                       \
    GLOAD_LDS16(ga_ + 64 * (long)K_DIM, la_ + 4096);                             \
    GLOAD_LDS16(ga_ + 128 * (long)K_DIM, la_ + 8192);                            \
    GLOAD_LDS16(ga_ + 192 * (long)K_DIM, la_ + 12288);                           \
    const short* gb_ = uB + (long)(TT) * BK + voff;                              \
    char* lb_ = ldsb + (SLOT_) * SLOT_SZ + 16384 + wave * 1024;                  \
    GLOAD_LDS16(gb_, lb_);                                                       \
    GLOAD_LDS16(gb_ + 64 * (long)K_DIM, lb_ + 4096);                             \
  } while (0)

// One K-tile: read 12 frags, stage, 32 MFMA, gate+barrier.
// VM: 6 = steady vmcnt(6), 0 = drain, -1 = none (last tile).
#define TILE2(SLOT_, STSLOT_, T, DO_ST, VM) do {                                 \
    const char* base_ = ldsb + (SLOT_) * SLOT_SZ;                                \
    _Pragma("unroll")                                                            \
    for (int mf_ = 0; mf_ < 8; ++mf_)                                            \
      af[mf_] = *(const bf16x8*)(base_ + wm * 8192 + mf_ * 1024 + physoff);      \
    _Pragma("unroll")                                                            \
    for (int nf_ = 0; nf_ < 4; ++nf_)                                            \
      bf[nf_] = *(const bf16x8*)(base_ + 16384 + wn * 4096 + nf_ * 1024 + physoff);\
    if (DO_ST) STAGE2(STSLOT_, (T) + 2);                                         \
    __builtin_amdgcn_s_setprio(1);                                               \
    _Pragma("unroll")                                                            \
    for (int mf_ = 0; mf_ < 8; ++mf_)                                            \
      _Pragma("unroll")                                                          \
      for (int nf_ = 0; nf_ < 4; ++nf_)                                          \
        acc[mf_][nf_] = __builtin_amdgcn_mfma_f32_16x16x32_bf16(                 \
            af[mf_], bf[nf_], acc[mf_][nf_], 0, 0, 0);                           \
    __builtin_amdgcn_s_setprio(0);                                               \
    if ((VM) == 6)      asm volatile("s_waitcnt vmcnt(6)" ::: "memory");         \
    else if ((VM) == 0) asm volatile("s_waitcnt vmcnt(0)" ::: "memory");         \
    if ((VM) >= 0) __builtin_amdgcn_s_barrier();                                 \
  } while (0)

  f32x4 acc[8][4];
#pragma unroll
  for (int i = 0; i < 8; ++i)
#pragma unroll
    for (int j = 0; j < 4; ++j) acc[i][j] = (f32x4)0.0f;

  bf16x8 af[8], bf[4];

  // ---- prologue: stage tiles 0 (slot 0) and 1 (slot 1) ----
  STAGE2(0, 0);
  STAGE2(1, 1);
  asm volatile("s_waitcnt vmcnt(6)" ::: "memory");   // tile 0 resident
  __builtin_amdgcn_s_barrier();

  // ---- main loop: 3 tiles per iteration, tiles 0..125 ----
  for (int tt = 0; tt < NKT / 3; ++tt) {             // 42 iters -> t 0..125
    const int t0 = 3 * tt;
    TILE2(0, 2, t0,     1, 6);
    TILE2(1, 0, t0 + 1, 1, 6);
    TILE2(2, 1, t0 + 2, 1, 6);
  }
  // ---- tail: tile 126 (slot 0, drain 127's loads), tile 127 (slot 1) ----
  TILE2(0, 0, NKT - 2, 0, 0);
  TILE2(1, 0, NKT - 1, 0, -1);
  __builtin_amdgcn_s_barrier();                      // seal before scratch use

#undef TILE2
#undef STAGE2

  // ---- epilogue: per-wave LDS transpose -> 128-B-segment f32x4 stores ----
  {
    char* scr = ldsb + wave * 8192;
    const int c0 = lane & 15;
    const int r0 = (lane >> 4) * 4;
    const int rd_row = lane >> 3;        // 0..7
    const int rd_ch  = (lane & 7) * 16;  // 16-B chunk within 128-B row
#pragma unroll
    for (int jp = 0; jp < 2; ++jp) {
      const long gcb = rowB0 + wn * 64 + jp * 32 + (lane & 7) * 4;
      const f32x4 bv4 = *(const f32x4*)&bias[gcb];
#pragma unroll
      for (int i = 0; i < 8; ++i) {
#pragma unroll
        for (int r = 0; r < 4; ++r) {
          *(float*)(scr + (r0 + r) * 144 + c0 * 4)      = acc[i][2 * jp + 0][r];
          *(float*)(scr + (r0 + r) * 144 + 64 + c0 * 4) = acc[i][2 * jp + 1][r];
        }
        f32x4 v0 = *(const f32x4*)(scr + rd_row * 144 + rd_ch);
        f32x4 v1 = *(const f32x4*)(scr + (8 + rd_row) * 144 + rd_ch);
        v0 += bv4;
        v1 += bv4;
#pragma unroll
        for (int e = 0; e < 4; ++e) {
          v0[e] = fmaxf(v0[e], 0.0f);
          v1[e] = fmaxf(v1[e], 0.0f);
        }
        const long gr = rowA0 + wm * 128 + i * 16;
        *(f32x4*)&Y[(gr + rd_row) * (long)N_DIM + gcb]     = v0;
        *(f32x4*)&Y[(gr + 8 + rd_row) * (long)N_DIM + gcb] = v1;
      }
    }
  }
}

// ---------------------------------------------------------------------------
// Fallback (only if ws too small): fp32 reg-staged 128^2 kernel.
// ---------------------------------------------------------------------------
#define FBM 128
#define FBK 32
#define FLDSS 40
__global__ __launch_bounds__(256) void fallback_gemm(
    const float* __restrict__ X, const float* __restrict__ W,
    const float* __restrict__ bias, float* __restrict__ Y) {
  __shared__ short As[FBM * FLDSS];
  __shared__ short Bs[FBM * FLDSS];
  const int tid = threadIdx.x, lane = tid & 63, wave = tid >> 6;
  const int wm = (wave >> 1) * 64, wn = (wave & 1) * 64;
  const long rowA0 = (long)blockIdx.y * FBM, rowB0 = (long)blockIdx.x * FBM;
  const int srow = tid >> 3, scol = (tid & 7) * 4;
  const float* Aptr = X + (rowA0 + srow) * (long)K_DIM + scol;
  const float* Bptr = W + (rowB0 + srow) * (long)K_DIM + scol;
  f32x4 ra[4], rb[4];
#pragma unroll
  for (int i = 0; i < 4; ++i) {
    ra[i] = *(const f32x4*)(Aptr + (long)i * 32 * K_DIM);
    rb[i] = *(const f32x4*)(Bptr + (long)i * 32 * K_DIM);
  }
  f32x4 acc[4][4];
#pragma unroll
  for (int i = 0; i < 4; ++i)
#pragma unroll
    for (int j = 0; j < 4; ++j) acc[i][j] = (f32x4)0.0f;
  for (int kt = 0; kt < K_DIM / FBK; ++kt) {
    __syncthreads();
#pragma unroll
    for (int i = 0; i < 4; ++i) {
      bf16x4v pa, pb;
#pragma unroll
      for (int j = 0; j < 4; ++j) {
        pa[j] = (short)__bfloat16_as_ushort(__float2bfloat16(ra[i][j]));
        pb[j] = (short)__bfloat16_as_ushort(__float2bfloat16(rb[i][j]));
      }
      *(bf16x4v*)&As[(i * 32 + srow) * FLDSS + scol] = pa;
      *(bf16x4v*)&Bs[(i * 32 + srow) * FLDSS + scol] = pb;
    }
    if (kt + 1 < K_DIM / FBK) {
      const float* An = Aptr + (kt + 1) * FBK;
      const float* Bn = Bptr + (kt + 1) * FBK;
#pragma unroll
      for (int i = 0; i < 4; ++i) {
        ra[i] = *(const f32x4*)(An + (long)i * 32 * K_DIM);
        rb[i] = *(const f32x4*)(Bn + (long)i * 32 * K_DIM);
      }
    }
    __syncthreads();
    bf16x8 af[4], bfr[4];
#pragma unroll
    for (int i = 0; i < 4; ++i) {
      af[i]  = *(const bf16x8*)&As[(wm + i * 16 + (lane & 15)) * FLDSS + (lane >> 4) * 8];
      bfr[i] = *(const bf16x8*)&Bs[(wn + i * 16 + (lane & 15)) * FLDSS + (lane >> 4) * 8];
    }
#pragma unroll
    for (int i = 0; i < 4; ++i)
#pragma unroll
      for (int j = 0; j < 4; ++j)
        acc[i][j] = __builtin_amdgcn_mfma_f32_16x16x32_bf16(af[i], bfr[j], acc[i][j], 0, 0, 0);
  }
  const int r0 = (lane >> 4) * 4, c0 = lane & 15;
#pragma unroll
  for (int j = 0; j < 4; ++j) {
    const long gc = rowB0 + wn + j * 16 + c0;
    const float bv = bias[gc];
#pragma unroll
    for (int i = 0; i < 4; ++i) {
      const long gr0 = rowA0 + wm + i * 16 + r0;
#pragma unroll
      for (int r = 0; r < 4; ++r) {
        float v = acc[i][j][r] + bv;
        Y[(gr0 + r) * (long)N_DIM + gc] = fmaxf(v, 0.0f);
      }
    }
  }
}

extern "C" void kernel_launch(void* const* d_in, const int* in_sizes, int n_in,
                              void* d_out, int out_size, void* d_ws, size_t ws_size,
                              hipStream_t stream) {
  const float* x = (const float*)d_in[0];
  const float* w = (const float*)d_in[1];
  const float* b = (const float*)d_in[2];
  float* y = (float*)d_out;

  const size_t need = (size_t)(NX + NW) * sizeof(short);
  if (ws_size >= need) {
    short* ws = (short*)d_ws;
    convert_bf16<<<2048, 256, 0, stream>>>(x, w, ws);
    dim3 grid(N_DIM / BN, M_DIM / BM);   // 32 x 32
    gemm2_bf16<<<grid, dim3(THREADS), 0, stream>>>(ws, ws + NX, b, y);
  } else {
    dim3 grid(N_DIM / FBM, M_DIM / FBM);
    fallback_gemm<<<grid, dim3(256), 0, stream>>>(x, w, b, y);
  }
}

// Round 15
// 251.444 us; speedup vs baseline: 1.1610x; 1.1610x over previous
//
#include <hip/hip_runtime.h>
#include <hip/hip_bf16.h>

typedef __attribute__((ext_vector_type(4))) float f32x4;
typedef __attribute__((ext_vector_type(8))) short bf16x8;
typedef __attribute__((ext_vector_type(4))) short bf16x4v;

#define M_DIM 8192
#define N_DIM 4096
#define K_DIM 4096
#define NX (M_DIM * K_DIM)
#define NW (N_DIM * K_DIM)

#define BM 256
#define BN 256
#define BK 64
#define NKT (K_DIM / BK)   /* 64 */
#define THREADS 512

#define GLOAD_LDS16(g, l)                                                        \
  __builtin_amdgcn_global_load_lds(                                              \
      (const __attribute__((address_space(1))) void*)(g),                        \
      (__attribute__((address_space(3))) void*)(l), 16, 0, 0)

// ---------------------------------------------------------------------------
// Pass 1: fp32 -> bf16 conversion of x and W into workspace.
// ---------------------------------------------------------------------------
__global__ __launch_bounds__(256) void convert_bf16(const float* __restrict__ x,
                                                    const float* __restrict__ w,
                                                    short* __restrict__ ws) {
  const long stride = (long)gridDim.x * blockDim.x;
  const long total8 = ((long)NX + NW) / 8;
  for (long i = blockIdx.x * (long)blockDim.x + threadIdx.x; i < total8; i += stride) {
    const long base = i * 8;
    const float* src = (base < NX) ? (x + base) : (w + (base - NX));
    short* dst = ws + base;
    f32x4 a = *(const f32x4*)src;
    f32x4 b = *(const f32x4*)(src + 4);
    bf16x8 o;
    o[0] = (short)__bfloat16_as_ushort(__float2bfloat16(a[0]));
    o[1] = (short)__bfloat16_as_ushort(__float2bfloat16(a[1]));
    o[2] = (short)__bfloat16_as_ushort(__float2bfloat16(a[2]));
    o[3] = (short)__bfloat16_as_ushort(__float2bfloat16(a[3]));
    o[4] = (short)__bfloat16_as_ushort(__float2bfloat16(b[0]));
    o[5] = (short)__bfloat16_as_ushort(__float2bfloat16(b[1]));
    o[6] = (short)__bfloat16_as_ushort(__float2bfloat16(b[2]));
    o[7] = (short)__bfloat16_as_ushort(__float2bfloat16(b[3]));
    *(bf16x8*)dst = o;
  }
}

// ---------------------------------------------------------------------------
// Pass 2 (champion, R10 schedule + R13 chunking): 256x256 bf16 GEMM, BK=64,
// 8 waves (2M x 4N), double-buffered LDS, 4 phases per K-tile, one trailing
// barrier each, no lgkm pins.  Staging of tile t+2: B halves at ph2 (B reads
// sealed by ph1's barrier), A halves at ph3 (A sealed by ph2's barrier) ->
// ~2 K-tiles of flight per load, issue spread 4+4, single vmcnt(8) gate per
// tile.  XOR slot swizzle; 8x8 super-tile XCD chunking; setprio; coalesced
// epilogue via per-wave LDS transpose.
// Y = relu(X @ W^T + b)
//
// LDS per buffer (64 KiB): A rows 0-255 at [0,32KB) (half0 rows 0-127,
// half1 rows 128-255), B likewise at [32KB,64KB). Rows 128 B, 8 slots of
// 16 B, phys slot = logical ^ (row&7).
//
// XCD chunking: workgroup lin -> XCD x = lin&7 (HW round-robin).  idx =
// lin>>3 in [0,64): by = (x>>1)*8 + (idx>>3), bx = (x&1)*8 + (idx&7).
// Each XCD's 64 blocks form an 8by x 8bx super-tile: A+B footprint
// 16+16 MB (was 8+32), B panels reused by 8 blocks in-XCD.
// ---------------------------------------------------------------------------
__global__ __launch_bounds__(THREADS, 2) void gemm256_bf16(
    const short* __restrict__ Abf,   /* [M][K] bf16 */
    const short* __restrict__ Bbf,   /* [N][K] bf16 */
    const float* __restrict__ bias,
    float* __restrict__ Y) {
  __shared__ short lds[2 * 32768];   /* 128 KiB */
  char* const ldsb = (char*)lds;

  const int tid  = threadIdx.x;
  const int lane = tid & 63;
  const int wave = tid >> 6;       // 0..7
  const int wm   = wave >> 2;      // 0..1  (M half)
  const int wn   = wave & 3;       // 0..3  (N quarter)

  // 8x8 super-tile XCD chunking (512 wgs = 8 XCDs x 64; bijective).
  const int lin = blockIdx.x + blockIdx.y * (N_DIM / BN);   // gridDim.x = 16
  const int xcd = lin & 7;
  const int idx = lin >> 3;        // 0..63
  const int by = (xcd >> 1) * 8 + (idx >> 3);   // 0..31
  const int bx = (xcd & 1) * 8 + (idx & 7);     // 0..15
  const long rowA0 = (long)by * BM;
  const long rowB0 = (long)bx * BN;

  // staging: one GLOAD issue = 512 thr x 16 B = 64 rows x 128 B.
  const int sg_col = (((lane & 7) ^ ((lane >> 3) & 7)) << 3);
  const int s_row  = wave * 8 + (lane >> 3);
  const int voff = s_row * K_DIM + sg_col;

  const short* uA = Abf + rowA0 * (long)K_DIM;
  const short* uB = Bbf + rowB0 * (long)K_DIM;

  // fragment-read per-lane byte offsets: row = frag*16 + (lane&15),
  // phys slot = kslot ^ (row&7) = kslot ^ (lane&7).
  const int offk0 = (lane & 15) * 128 + ((((lane >> 4)) ^ (lane & 7)) << 4);
  const int offk1 = (lane & 15) * 128 + (((4 + (lane >> 4)) ^ (lane & 7)) << 4);

// stage one half-tile (2 gloads). HALF: 0 = A rows 0-127, 1 = A rows 128-255,
// 2 = B rows 0-127, 3 = B rows 128-255.
#define STAGE_HALF(BOFF_, HALF_, TT) do {                                        \
    const short* u_ = ((HALF_) < 2 ? uA : uB) +                                  \
                      (long)(((HALF_) & 1) * 128) * K_DIM + (long)(TT) * BK;     \
    char* l_ = ldsb + (BOFF_) + ((HALF_) < 2 ? 0 : 32768) +                      \
               ((HALF_) & 1) * 16384 + wave * 1024;                              \
    GLOAD_LDS16(u_ + voff, l_);                                                  \
    GLOAD_LDS16(u_ + 64 * K_DIM + voff, l_ + 8192);                              \
  } while (0)

#define PH_READ_A(DST, BOFF_, MADD) do {                                         \
    const char* pa_ = ldsb + (BOFF_) + wm * 16384 + (MADD);                      \
    _Pragma("unroll")                                                            \
    for (int m_ = 0; m_ < 4; ++m_) {                                             \
      DST[m_][0] = *(const bf16x8*)(pa_ + m_ * 2048 + offk0);                    \
      DST[m_][1] = *(const bf16x8*)(pa_ + m_ * 2048 + offk1);                    \
    }                                                                            \
  } while (0)

#define PH_READ_B(DST, BOFF_, NADD) do {                                         \
    const char* pb_ = ldsb + (BOFF_) + 32768 + wn * 8192 + (NADD);               \
    _Pragma("unroll")                                                            \
    for (int n_ = 0; n_ < 2; ++n_) {                                             \
      DST[n_][0] = *(const bf16x8*)(pb_ + n_ * 2048 + offk0);                    \
      DST[n_][1] = *(const bf16x8*)(pb_ + n_ * 2048 + offk1);                    \
    }                                                                            \
  } while (0)

#define MFMA16(AF, BF, MB, NB) do {                                              \
    __builtin_amdgcn_s_setprio(1);                                               \
    _Pragma("unroll")                                                            \
    for (int kk_ = 0; kk_ < 2; ++kk_)                                            \
      _Pragma("unroll")                                                          \
      for (int m_ = 0; m_ < 4; ++m_)                                             \
        _Pragma("unroll")                                                        \
        for (int n_ = 0; n_ < 2; ++n_)                                           \
          acc[(MB) + m_][(NB) + n_] = __builtin_amdgcn_mfma_f32_16x16x32_bf16(   \
              AF[m_][kk_], BF[n_][kk_], acc[(MB) + m_][(NB) + n_], 0, 0, 0);     \
    __builtin_amdgcn_s_setprio(0);                                               \
  } while (0)

// One K-tile: 4 phases, one trailing barrier each.
// VM: 8 = steady vmcnt(8), 0 = drain, -1 = none (last tile).
#define TILE(BOFF_, T, DO_ST, VM) do {                                           \
    /* ph0: read A m0-3 + B n0-1; MFMA (m0-3, n0-1) */                           \
    PH_READ_A(af, BOFF_, 0);                                                     \
    PH_READ_B(bfr01, BOFF_, 0);                                                  \
    MFMA16(af, bfr01, 0, 0);                                                     \
    __builtin_amdgcn_s_barrier();                                                \
    /* ph1: read B n2-3; MFMA (m0-3, n2-3) */                                    \
    PH_READ_B(bfr23, BOFF_, 4096);                                               \
    MFMA16(af, bfr23, 0, 2);                                                     \
    __builtin_amdgcn_s_barrier();                                                \
    /* ph2: read A m4-7; stage B(T+2); MFMA (m4-7, n0-1) */                      \
    PH_READ_A(af, BOFF_, 8192);                                                  \
    if (DO_ST) { STAGE_HALF(BOFF_, 2, (T) + 2); STAGE_HALF(BOFF_, 3, (T) + 2); } \
    MFMA16(af, bfr01, 4, 0);                                                     \
    __builtin_amdgcn_s_barrier();                                                \
    /* ph3: stage A(T+2); MFMA (m4-7, n2-3); counted vmcnt gate */               \
    if (DO_ST) { STAGE_HALF(BOFF_, 0, (T) + 2); STAGE_HALF(BOFF_, 1, (T) + 2); } \
    MFMA16(af, bfr23, 4, 2);                                                     \
    if ((VM) == 8)      asm volatile("s_waitcnt vmcnt(8)" ::: "memory");         \
    else if ((VM) == 0) asm volatile("s_waitcnt vmcnt(0)" ::: "memory");         \
    if ((VM) >= 0) __builtin_amdgcn_s_barrier();                                 \
  } while (0)

  f32x4 acc[8][4];
#pragma unroll
  for (int i = 0; i < 8; ++i)
#pragma unroll
    for (int j = 0; j < 4; ++j) acc[i][j] = (f32x4)0.0f;

  bf16x8 af[4][2], bfr01[2][2], bfr23[2][2];

  // ---- prologue: stage tiles 0 and 1 fully ----
  STAGE_HALF(0, 0, 0);
  STAGE_HALF(0, 1, 0);
  STAGE_HALF(0, 2, 0);
  STAGE_HALF(0, 3, 0);
  STAGE_HALF(65536, 2, 1);
  STAGE_HALF(65536, 3, 1);
  STAGE_HALF(65536, 0, 1);
  STAGE_HALF(65536, 1, 1);
  asm volatile("s_waitcnt vmcnt(8)" ::: "memory");   // tile 0 resident
  __builtin_amdgcn_s_barrier();

  // ---- main loop: 2 tiles per iteration, tiles 0..61 ----
  for (int tp = 0; tp < NKT / 2 - 1; ++tp) {
    const int t0 = 2 * tp;
    TILE(0,     t0,     1, 8);
    TILE(65536, t0 + 1, 1, 8);
  }
  // ---- tail: tile 62 (no stage, drain 63's loads), tile 63 ----
  TILE(0,     NKT - 2, 0, 0);
  TILE(65536, NKT - 1, 0, -1);

#undef TILE
#undef MFMA16
#undef PH_READ_B
#undef PH_READ_A
#undef STAGE_HALF

  // ---- epilogue: per-wave LDS transpose -> 128-B-segment f32x4 stores ----
  {
    char* scr = ldsb + wave * 8192;
    const int c0 = lane & 15;
    const int r0 = (lane >> 4) * 4;
    const int rd_row = lane >> 3;        // 0..7
    const int rd_ch  = (lane & 7) * 16;  // 16-B chunk within 128-B row
#pragma unroll
    for (int jp = 0; jp < 2; ++jp) {
      const long gcb = rowB0 + wn * 64 + jp * 32 + (lane & 7) * 4;
      const f32x4 bv4 = *(const f32x4*)&bias[gcb];
#pragma unroll
      for (int i = 0; i < 8; ++i) {
#pragma unroll
        for (int r = 0; r < 4; ++r) {
          *(float*)(scr + (r0 + r) * 144 + c0 * 4)      = acc[i][2 * jp + 0][r];
          *(float*)(scr + (r0 + r) * 144 + 64 + c0 * 4) = acc[i][2 * jp + 1][r];
        }
        f32x4 v0 = *(const f32x4*)(scr + rd_row * 144 + rd_ch);
        f32x4 v1 = *(const f32x4*)(scr + (8 + rd_row) * 144 + rd_ch);
        v0 += bv4;
        v1 += bv4;
#pragma unroll
        for (int e = 0; e < 4; ++e) {
          v0[e] = fmaxf(v0[e], 0.0f);
          v1[e] = fmaxf(v1[e], 0.0f);
        }
        const long gr = rowA0 + wm * 128 + i * 16;
        *(f32x4*)&Y[(gr + rd_row) * (long)N_DIM + gcb]     = v0;
        *(f32x4*)&Y[(gr + 8 + rd_row) * (long)N_DIM + gcb] = v1;
      }
    }
  }
}

// ---------------------------------------------------------------------------
// Fallback (only if ws too small): fp32 reg-staged 128^2 kernel.
// ---------------------------------------------------------------------------
#define FBM 128
#define FBK 32
#define FLDSS 40
__global__ __launch_bounds__(256) void fallback_gemm(
    const float* __restrict__ X, const float* __restrict__ W,
    const float* __restrict__ bias, float* __restrict__ Y) {
  __shared__ short As[FBM * FLDSS];
  __shared__ short Bs[FBM * FLDSS];
  const int tid = threadIdx.x, lane = tid & 63, wave = tid >> 6;
  const int wm = (wave >> 1) * 64, wn = (wave & 1) * 64;
  const long rowA0 = (long)blockIdx.y * FBM, rowB0 = (long)blockIdx.x * FBM;
  const int srow = tid >> 3, scol = (tid & 7) * 4;
  const float* Aptr = X + (rowA0 + srow) * (long)K_DIM + scol;
  const float* Bptr = W + (rowB0 + srow) * (long)K_DIM + scol;
  f32x4 ra[4], rb[4];
#pragma unroll
  for (int i = 0; i < 4; ++i) {
    ra[i] = *(const f32x4*)(Aptr + (long)i * 32 * K_DIM);
    rb[i] = *(const f32x4*)(Bptr + (long)i * 32 * K_DIM);
  }
  f32x4 acc[4][4];
#pragma unroll
  for (int i = 0; i < 4; ++i)
#pragma unroll
    for (int j = 0; j < 4; ++j) acc[i][j] = (f32x4)0.0f;
  for (int kt = 0; kt < K_DIM / FBK; ++kt) {
    __syncthreads();
#pragma unroll
    for (int i = 0; i < 4; ++i) {
      bf16x4v pa, pb;
#pragma unroll
      for (int j = 0; j < 4; ++j) {
        pa[j] = (short)__bfloat16_as_ushort(__float2bfloat16(ra[i][j]));
        pb[j] = (short)__bfloat16_as_ushort(__float2bfloat16(rb[i][j]));
      }
      *(bf16x4v*)&As[(i * 32 + srow) * FLDSS + scol] = pa;
      *(bf16x4v*)&Bs[(i * 32 + srow) * FLDSS + scol] = pb;
    }
    if (kt + 1 < K_DIM / FBK) {
      const float* An = Aptr + (kt + 1) * FBK;
      const float* Bn = Bptr + (kt + 1) * FBK;
#pragma unroll
      for (int i = 0; i < 4; ++i) {
        ra[i] = *(const f32x4*)(An + (long)i * 32 * K_DIM);
        rb[i] = *(const f32x4*)(Bn + (long)i * 32 * K_DIM);
      }
    }
    __syncthreads();
    bf16x8 af[4], bfr[4];
#pragma unroll
    for (int i = 0; i < 4; ++i) {
      af[i]  = *(const bf16x8*)&As[(wm + i * 16 + (lane & 15)) * FLDSS + (lane >> 4) * 8];
      bfr[i] = *(const bf16x8*)&Bs[(wn + i * 16 + (lane & 15)) * FLDSS + (lane >> 4) * 8];
    }
#pragma unroll
    for (int i = 0; i < 4; ++i)
#pragma unroll
      for (int j = 0; j < 4; ++j)
        acc[i][j] = __builtin_amdgcn_mfma_f32_16x16x32_bf16(af[i], bfr[j], acc[i][j], 0, 0, 0);
  }
  const int r0 = (lane >> 4) * 4, c0 = lane & 15;
#pragma unroll
  for (int j = 0; j < 4; ++j) {
    const long gc = rowB0 + wn + j * 16 + c0;
    const float bv = bias[gc];
#pragma unroll
    for (int i = 0; i < 4; ++i) {
      const long gr0 = rowA0 + wm + i * 16 + r0;
#pragma unroll
      for (int r = 0; r < 4; ++r) {
        float v = acc[i][j][r] + bv;
        Y[(gr0 + r) * (long)N_DIM + gc] = fmaxf(v, 0.0f);
      }
    }
  }
}

extern "C" void kernel_launch(void* const* d_in, const int* in_sizes, int n_in,
                              void* d_out, int out_size, void* d_ws, size_t ws_size,
                              hipStream_t stream) {
  const float* x = (const float*)d_in[0];
  const float* w = (const float*)d_in[1];
  const float* b = (const float*)d_in[2];
  float* y = (float*)d_out;

  const size_t need = (size_t)(NX + NW) * sizeof(short);
  if (ws_size >= need) {
    short* ws = (short*)d_ws;
    convert_bf16<<<2048, 256, 0, stream>>>(x, w, ws);
    dim3 grid(N_DIM / BN, M_DIM / BM);
    gemm256_bf16<<<grid, dim3(THREADS), 0, stream>>>(ws, ws + NX, b, y);
  } else {
    dim3 grid(N_DIM / FBM, M_DIM / FBM);
    fallback_gemm<<<grid, dim3(256), 0, stream>>>(x, w, b, y);
  }
}